// Round 1
// baseline (311.532 us; speedup 1.0000x reference)
//
#include <hip/hip_runtime.h>
#include <hip/hip_bf16.h>
#include <cstdint>
#include <cstddef>

// ---------------------------------------------------------------------------
// SelfAttention: x[8,256,2048] fp32, W*[2048,2048], b*[2048]
//   q = x @ Wq^T + bq   (per (b,c) row)         -> [8,256,2048]
//   S[b,l,m] = scale * sum_c q[b,c,l]*k[b,c,m]  -> [8,2048,2048]
//   P = softmax_m(S)
//   out[b,c,l] = sum_m v[b,c,m]*P[b,l,m]        -> [8,256,2048] fp32
//
// Pipeline (all bf16 MFMA, m97-style 128x128 tile, global_load_lds width=16):
//   1. cvt fp32->bf16: x, Wq, Wk, Wv
//   2. GEMM_bt EPI=bias:  qkv[z] = xb . Wb[z]^T + b[z]      (z=0..2)
//   3. transpose q,k -> qT,kT (for K-dim = channel contraction)
//   4. GEMM_bt EPI=scale: S[b]   = qT[:,b] . kT[:,b]^T * scale (K=256)
//   5. row softmax in place on S (bf16)
//   6. GEMM_bt EPI=f32:  out[b]  = v[b] . S[b]^T             (K=2048)
// ---------------------------------------------------------------------------

typedef __bf16 bf16_t;
typedef __bf16 bf16x8 __attribute__((ext_vector_type(8)));
typedef __bf16 bf16x4 __attribute__((ext_vector_type(4)));
typedef float floatx4 __attribute__((ext_vector_type(4)));

#define GLD_LDS16(gptr, lptr)                                                  \
  __builtin_amdgcn_global_load_lds(                                            \
      (const __attribute__((address_space(1))) void*)(gptr),                   \
      (__attribute__((address_space(3))) void*)(lptr), 16, 0, 0)

// ---------------- fp32 -> bf16 conversion (vectorized) ----------------------
__global__ __launch_bounds__(256) void cvt_f32_bf16_k(const float* __restrict__ src,
                                                      bf16_t* __restrict__ dst) {
  const int i = (blockIdx.x * 256 + threadIdx.x) * 4;
  const float4 v = *reinterpret_cast<const float4*>(src + i);
  bf16x4 o;
  o[0] = (bf16_t)v.x; o[1] = (bf16_t)v.y; o[2] = (bf16_t)v.z; o[3] = (bf16_t)v.w;
  *reinterpret_cast<bf16x4*>(dst + i) = o;
}

// ---------------- generic C[i,j] = sum_k A[i,k]*B[j,k] ----------------------
// A: rows from blockIdx.x*128, row-major, leading dim lda (bf16)
// B: rows from blockIdx.y*128, row-major, leading dim ldb (bf16)
// blockIdx.z batches: A += z*bsA, B += z*bsB, C += z*bsC, bias += z*bsBias
// EPI: 0 = bf16 out + bias[j]; 1 = bf16 out * scale; 2 = fp32 out
template <int EPI>
__global__ __launch_bounds__(256) void gemm_bt(
    const bf16_t* __restrict__ Abase, const bf16_t* __restrict__ Bbase,
    void* __restrict__ Cbase, const float* __restrict__ biasBase, int K,
    int lda, int ldb, int ldc, long bsA, long bsB, long bsC, int bsBias,
    float scale) {
  __shared__ __align__(16) bf16_t lds_a[128 * 32];
  __shared__ __align__(16) bf16_t lds_b[128 * 32];

  const int tid = threadIdx.x;
  const int lane = tid & 63;
  const int wid = tid >> 6;
  const int brow = blockIdx.x * 128;
  const int bcol = blockIdx.y * 128;
  const int wr = wid >> 1, wc = wid & 1;  // wave -> 64x64 quadrant

  const bf16_t* A = Abase + (long)blockIdx.z * bsA;
  const bf16_t* B = Bbase + (long)blockIdx.z * bsB;

  floatx4 acc[4][4];
#pragma unroll
  for (int m = 0; m < 4; m++)
#pragma unroll
    for (int n = 0; n < 4; n++) acc[m][n] = (floatx4)0.f;

  // staging geometry: tile 128x32 bf16 = 8KB = 8 chunks of 1KB (one per
  // wave-call, lane l -> 16B at chunk_base + l*16). wave w stages chunks
  // {2w, 2w+1} of A and of B.
  const int c0 = wid * 2, c1 = wid * 2 + 1;
  const int srow0 = c0 * 16 + (lane >> 2);
  const int srow1 = c1 * 16 + (lane >> 2);
  const int skoff = (lane & 3) * 8;

  for (int kk = 0; kk < K; kk += 32) {
    GLD_LDS16(A + (size_t)(brow + srow0) * lda + kk + skoff, lds_a + c0 * 512);
    GLD_LDS16(A + (size_t)(brow + srow1) * lda + kk + skoff, lds_a + c1 * 512);
    GLD_LDS16(B + (size_t)(bcol + srow0) * ldb + kk + skoff, lds_b + c0 * 512);
    GLD_LDS16(B + (size_t)(bcol + srow1) * ldb + kk + skoff, lds_b + c1 * 512);
    __syncthreads();  // drains vmcnt before barrier (compiler-inserted)

    bf16x8 af[4], bfr[4];
#pragma unroll
    for (int m = 0; m < 4; m++)
      af[m] = *(const bf16x8*)&lds_a[(wr * 64 + m * 16 + (lane & 15)) * 32 +
                                     (lane >> 4) * 8];
#pragma unroll
    for (int n = 0; n < 4; n++)
      bfr[n] = *(const bf16x8*)&lds_b[(wc * 64 + n * 16 + (lane & 15)) * 32 +
                                      (lane >> 4) * 8];
#pragma unroll
    for (int m = 0; m < 4; m++)
#pragma unroll
      for (int n = 0; n < 4; n++)
        acc[m][n] =
            __builtin_amdgcn_mfma_f32_16x16x32_bf16(af[m], bfr[n], acc[m][n], 0, 0, 0);
    __syncthreads();
  }

  // epilogue: C/D layout col = lane&15, row = (lane>>4)*4 + r  [m89]
  const int r0 = (lane >> 4) * 4;
  const int cc = lane & 15;
  bf16_t* Cb = (bf16_t*)Cbase + (long)blockIdx.z * bsC;
  float* Cf = (float*)Cbase + (long)blockIdx.z * bsC;
  const float* bias =
      (EPI == 0) ? (biasBase + (long)blockIdx.z * bsBias) : nullptr;

#pragma unroll
  for (int n = 0; n < 4; n++) {
    const int gj = bcol + wc * 64 + n * 16 + cc;
    float badd = 0.f;
    if constexpr (EPI == 0) badd = bias[gj];
#pragma unroll
    for (int m = 0; m < 4; m++) {
      const int gi = brow + wr * 64 + m * 16 + r0;
#pragma unroll
      for (int r = 0; r < 4; r++) {
        const float v = acc[m][n][r];
        if constexpr (EPI == 0)
          Cb[(size_t)(gi + r) * ldc + gj] = (bf16_t)(v + badd);
        else if constexpr (EPI == 1)
          Cb[(size_t)(gi + r) * ldc + gj] = (bf16_t)(v * scale);
        else
          Cf[(size_t)(gi + r) * ldc + gj] = v;
      }
    }
  }
}

// ---------------- 2048x2048 bf16 transpose (64x64 LDS tiles) ----------------
__global__ __launch_bounds__(256) void transpose2k(const bf16_t* __restrict__ inb,
                                                   bf16_t* __restrict__ outb) {
  __shared__ bf16_t t[64][65];
  const bf16_t* in = inb + (long)blockIdx.z * (4l * 1024 * 1024);
  bf16_t* out = outb + (long)blockIdx.z * (4l * 1024 * 1024);
  const int bx = blockIdx.x * 64, by = blockIdx.y * 64;
  const int tx = threadIdx.x, ty = threadIdx.y;  // (64,4)
  for (int r = ty; r < 64; r += 4)
    t[r][tx] = in[(size_t)(by + r) * 2048 + bx + tx];
  __syncthreads();
  for (int r = ty; r < 64; r += 4)
    out[(size_t)(bx + r) * 2048 + by + tx] = t[tx][r];
}

// ---------------- in-place row softmax over 2048 bf16 -----------------------
__global__ __launch_bounds__(256) void softmax_rows(bf16_t* __restrict__ S) {
  bf16_t* p = S + (size_t)blockIdx.x * 2048;
  const int tid = threadIdx.x;
  const int lane = tid & 63, wid = tid >> 6;
  __shared__ float redm[4], reds[4];

  bf16x8 v8 = *(const bf16x8*)&p[tid * 8];
  float f[8];
#pragma unroll
  for (int i = 0; i < 8; i++) f[i] = (float)v8[i];
  float mx = f[0];
#pragma unroll
  for (int i = 1; i < 8; i++) mx = fmaxf(mx, f[i]);
  for (int o = 32; o; o >>= 1) mx = fmaxf(mx, __shfl_xor(mx, o));
  if (lane == 0) redm[wid] = mx;
  __syncthreads();
  mx = fmaxf(fmaxf(redm[0], redm[1]), fmaxf(redm[2], redm[3]));

  float s = 0.f;
#pragma unroll
  for (int i = 0; i < 8; i++) {
    f[i] = __expf(f[i] - mx);
    s += f[i];
  }
  for (int o = 32; o; o >>= 1) s += __shfl_xor(s, o);
  if (lane == 0) reds[wid] = s;
  __syncthreads();
  s = reds[0] + reds[1] + reds[2] + reds[3];
  const float inv = 1.f / s;

  bf16x8 o8;
#pragma unroll
  for (int i = 0; i < 8; i++) o8[i] = (bf16_t)(f[i] * inv);
  *(bf16x8*)&p[tid * 8] = o8;
}

// ---------------------------------------------------------------------------
extern "C" void kernel_launch(void* const* d_in, const int* in_sizes, int n_in,
                              void* d_out, int out_size, void* d_ws,
                              size_t ws_size, hipStream_t stream) {
  const float* x = (const float*)d_in[0];
  const float* Wq = (const float*)d_in[1];
  const float* bq = (const float*)d_in[2];
  const float* Wk = (const float*)d_in[3];
  const float* bk = (const float*)d_in[4];
  const float* Wv = (const float*)d_in[5];
  const float* bv = (const float*)d_in[6];
  float* out = (float*)d_out;

  constexpr long M4 = 4l * 1024 * 1024;  // 2048*2048 elements
  bf16_t* ws = (bf16_t*)d_ws;
  bf16_t* xb = ws;                //  1*M4  x bf16          [bc, l]
  bf16_t* Wb = ws + M4;           //  3*M4  Wq,Wk,Wv bf16   [m, l]
  bf16_t* qkv = ws + 4 * M4;      //  3*M4  q,k,v bf16      [bc, m]
  bf16_t* tT = ws + 7 * M4;       //  2*M4  qT,kT bf16      [m, bc]
  bf16_t* S = ws + 9 * M4;        //  8*M4  S/P bf16        [b][l][m]
  float* biasw = (float*)(ws + 17 * M4);  // 3*2048 fp32
  const float scale = 0.022097086912079608f;  // 1/sqrt(2048)

  // 1. convert inputs to bf16
  dim3 cg(M4 / 4 / 256);
  cvt_f32_bf16_k<<<cg, 256, 0, stream>>>(x, xb);
  cvt_f32_bf16_k<<<cg, 256, 0, stream>>>(Wq, Wb);
  cvt_f32_bf16_k<<<cg, 256, 0, stream>>>(Wk, Wb + M4);
  cvt_f32_bf16_k<<<cg, 256, 0, stream>>>(Wv, Wb + 2 * M4);
  hipMemcpyAsync(biasw, bq, 2048 * 4, hipMemcpyDeviceToDevice, stream);
  hipMemcpyAsync(biasw + 2048, bk, 2048 * 4, hipMemcpyDeviceToDevice, stream);
  hipMemcpyAsync(biasw + 4096, bv, 2048 * 4, hipMemcpyDeviceToDevice, stream);

  // 2. qkv[z] = xb . W[z]^T + bias[z]   (M=N=K=2048)
  gemm_bt<0><<<dim3(16, 16, 3), 256, 0, stream>>>(
      xb, Wb, qkv, biasw, 2048, 2048, 2048, 2048, 0l, M4, M4, 2048, 0.f);

  // 3. qT,kT = transpose(q,k)
  transpose2k<<<dim3(32, 32, 2), dim3(64, 4), 0, stream>>>(qkv, tT);

  // 4. S[b] = scale * qT[:, b*256:+256] . kT[:, b*256:+256]^T   (K=256)
  gemm_bt<1><<<dim3(16, 16, 8), 256, 0, stream>>>(
      tT, tT + M4, S, nullptr, 256, 2048, 2048, 2048, 256l, 256l, M4, 0, scale);

  // 5. P = softmax_rows(S), in place (16384 rows of 2048)
  softmax_rows<<<dim3(8 * 2048), 256, 0, stream>>>(S);

  // 6. out[b] = v[b] . P[b]^T   (M=256, N=2048, K=2048), fp32 out
  gemm_bt<2><<<dim3(2, 16, 8), 256, 0, stream>>>(
      qkv + 2 * M4, S, out, nullptr, 2048, 2048, 2048, 2048, 256l * 2048, M4,
      256l * 2048, 0, 0.f);
}